// Round 13
// baseline (114.204 us; speedup 1.0000x reference)
//
#include <hip/hip_runtime.h>
#include <hip/hip_bf16.h>

// Problem constants
#define BB 2
#define NN 512
#define P0 16
#define P1 32
#define P2 32
#define HH 128

typedef __attribute__((ext_vector_type(8))) short bf16x8;
typedef __attribute__((ext_vector_type(4))) float f32x4;
typedef __attribute__((ext_vector_type(4))) unsigned u32x4;

__device__ __forceinline__ unsigned pkbf(float lo, float hi) {
  __hip_bfloat162 h = __float22bfloat162_rn(float2{lo, hi});
  unsigned r;
  __builtin_memcpy(&r, &h, 4);
  return r;
}

__device__ __forceinline__ float sigm(float x) {
  return __builtin_amdgcn_rcpf(1.0f + __expf(-x));
}

__device__ __forceinline__ bf16x8 pack2(f32x4 a, f32x4 b) {
  u32x4 u;
  u[0] = pkbf(a[0], a[1]);
  u[1] = pkbf(a[2], a[3]);
  u[2] = pkbf(b[0], b[1]);
  u[3] = pkbf(b[2], b[3]);
  return __builtin_bit_cast(bf16x8, u);
}

// ---------------------------------------------------------------------------
// Arity-2, PAIRED, 8-wave blocks (occupancy experiment). Block (b,i), 512 thr:
//  * 8 waves x 2 iters x 16 lanes cover j = i+1..i+256 (ring); each pair
//    computes out(i,j) AND out(j,i) from shared fragments.
//  * bias1 lives in LDS (frees 32 VGPRs -> target <=85 = 6 waves/SIMD tier).
//  * W1 staging amortized over 2x work vs 256-thread blocks.
//  * complete in-block arity-1 reduction + fused tail (arity-1 MLP, diagonal).
// NOTE: no __launch_bounds__ 2nd arg (round-5: (256,4) => 64-VGPR spill).
// ---------------------------------------------------------------------------
__global__ __launch_bounds__(512) void k_arity2(
    const float* __restrict__ x0, const float* __restrict__ x1,
    const float* __restrict__ x2,
    const float* __restrict__ W1, const float* __restrict__ b1,
    const float* __restrict__ W2, const float* __restrict__ b2,
    const float* __restrict__ W1_1, const float* __restrict__ b1_1,
    const float* __restrict__ W2_1, const float* __restrict__ b2_1,
    float* __restrict__ out1, float* __restrict__ out2) {
  __shared__ __align__(16) short lw[32 * 64 * 8];  // W1 frags: 32 KiB
  __shared__ __align__(16) float lb1[HH];          // bias1 broadcast
  __shared__ float pm[8][32], pn[8][32];           // reduction partials
  __shared__ float in1[112], in2[128];             // tail MLP inputs
  __shared__ float hid1[HH], hid2[HH];             // tail hidden layers

  const int tid = threadIdx.x;
  const int bid = blockIdx.x;  // 0..1023
  const int b = bid >> 9;      // 0..1
  const int i = bid & 511;     // 0..511

  // Stage W1 fragments to LDS (pre-swizzled to MFMA fragment order).
  for (int c = tid; c < 2048; c += 512) {
    const int l = c & 63, th = (c >> 6) & 7, s = c >> 9;
    const int fm = l & 15, fb = l >> 4;
    const int h = 16 * th + fm;
    float v[8];
#pragma unroll
    for (int e = 0; e < 8; ++e) {
      const int k = 32 * s + 4 * fb + (e & 3) + 16 * (e >> 2);
      v[e] = W1[k * HH + h];
    }
    unsigned* dst = (unsigned*)&lw[c * 8];
#pragma unroll
    for (int t = 0; t < 4; ++t) dst[t] = pkbf(v[2 * t], v[2 * t + 1]);
  }
  if (tid < HH) lb1[tid] = b1[tid];

  const int lane = tid & 63;
  const int wv = tid >> 6;  // 0..7
  const int m = lane & 15, bq = lane >> 4;

  // W2^T fragments in registers: A2[p][h], p = 16*pt + m
  bf16x8 w2f[2][4];
#pragma unroll
  for (int pt = 0; pt < 2; ++pt) {
#pragma unroll
    for (int s = 0; s < 4; ++s) {
      const int p = 16 * pt + m;
      float v[8];
#pragma unroll
      for (int e = 0; e < 8; ++e) {
        const int h = 32 * s + 4 * bq + (e & 3) + 16 * (e >> 2);
        v[e] = W2[h * P2 + p];
      }
      u32x4 u;
#pragma unroll
      for (int t = 0; t < 4; ++t) u[t] = pkbf(v[2 * t], v[2 * t + 1]);
      w2f[pt][s] = __builtin_bit_cast(bf16x8, u);
    }
  }

  f32x4 bias2[2];
#pragma unroll
  for (int pt = 0; pt < 2; ++pt)
#pragma unroll
    for (int r = 0; r < 4; ++r) bias2[pt][r] = b2[16 * pt + 4 * bq + r];

  // x1[b,i,:] fragment, constant over the block
  const float* x1bi = x1 + ((size_t)b * NN + i) * P1;
  const bf16x8 f1 = pack2(*(const f32x4*)(x1bi + 4 * bq),
                          *(const f32x4*)(x1bi + 16 + 4 * bq));

  __syncthreads();

  const bf16x8* wl = (const bf16x8*)lw;
  const size_t rowI = (size_t)b * NN + i;

  // Fused arity-1 reduction partials (channels 4bq..4bq+3 and 16+4bq..).
  f32x4 pmx0 = {0.f, 0.f, 0.f, 0.f}, pmx1 = {0.f, 0.f, 0.f, 0.f};
  f32x4 pmn0 = {1.f, 1.f, 1.f, 1.f}, pmn1 = {1.f, 1.f, 1.f, 1.f};

#pragma unroll
  for (int it = 0; it < 2; ++it) {
    const int j = (i + 1 + (it * 8 + wv) * 16 + m) & 511;
    const int j2 = (j + 256) & 511;  // other-half row for reduction only

    const float* p0 = x2 + (rowI * NN + j) * P2;                  // x2[b,i,j,:]
    const float* p2 = x2 + (((size_t)b * NN + j) * NN + i) * P2;  // x2[b,j,i,:]
    const float* p3 = x1 + ((size_t)b * NN + j) * P1;             // x1[b,j,:]
    const float* p4 = x2 + (rowI * NN + j2) * P2;                 // x2[b,i,j2,:]
    const f32x4 c0a = *(const f32x4*)(p0 + 4 * bq), c0b = *(const f32x4*)(p0 + 16 + 4 * bq);
    const f32x4 c2a = *(const f32x4*)(p2 + 4 * bq), c2b = *(const f32x4*)(p2 + 16 + 4 * bq);
    const f32x4 c3a = *(const f32x4*)(p3 + 4 * bq), c3b = *(const f32x4*)(p3 + 16 + 4 * bq);
    const f32x4 c4a = *(const f32x4*)(p4 + 4 * bq), c4b = *(const f32x4*)(p4 + 16 + 4 * bq);

    // Reduction: c0 (ring j, never diagonal) unconditional; c4 masked at j2==i.
    {
      const bool dg = (j2 == i);
#pragma unroll
      for (int r = 0; r < 4; ++r) {
        pmx0[r] = fmaxf(pmx0[r], fmaxf(c0a[r], dg ? 0.0f : c4a[r]));
        pmx1[r] = fmaxf(pmx1[r], fmaxf(c0b[r], dg ? 0.0f : c4b[r]));
        pmn0[r] = fminf(pmn0[r], fminf(c0a[r], dg ? 1.0f : c4a[r]));
        pmn1[r] = fminf(pmn1[r], fminf(c0b[r], dg ? 1.0f : c4b[r]));
      }
    }

    const bf16x8 f0 = pack2(c0a, c0b);
    const bf16x8 f2 = pack2(c2a, c2b);
    const bf16x8 f3 = pack2(c3a, c3b);

    // ---- DIRECT: out(i,j); in = [f0, f1, f2, f3] ----
    {
      f32x4 acc[8];
#pragma unroll
      for (int th = 0; th < 8; ++th) {
        const f32x4 bi = *(const f32x4*)&lb1[16 * th + 4 * bq];
        acc[th] = __builtin_amdgcn_mfma_f32_16x16x32_bf16(wl[(0 + th) * 64 + lane], f0, bi, 0, 0, 0);
      }
#pragma unroll
      for (int th = 0; th < 8; ++th)
        acc[th] = __builtin_amdgcn_mfma_f32_16x16x32_bf16(wl[(8 + th) * 64 + lane], f1, acc[th], 0, 0, 0);
#pragma unroll
      for (int th = 0; th < 8; ++th)
        acc[th] = __builtin_amdgcn_mfma_f32_16x16x32_bf16(wl[(16 + th) * 64 + lane], f2, acc[th], 0, 0, 0);
#pragma unroll
      for (int th = 0; th < 8; ++th)
        acc[th] = __builtin_amdgcn_mfma_f32_16x16x32_bf16(wl[(24 + th) * 64 + lane], f3, acc[th], 0, 0, 0);

      f32x4 acc2[2];
#pragma unroll
      for (int pt = 0; pt < 2; ++pt) acc2[pt] = bias2[pt];
#pragma unroll
      for (int s = 0; s < 4; ++s) {
        float sv[8];
#pragma unroll
        for (int e = 0; e < 4; ++e) {
          sv[e] = sigm(acc[2 * s][e]);
          sv[4 + e] = sigm(acc[2 * s + 1][e]);
        }
        u32x4 u;
#pragma unroll
        for (int t = 0; t < 4; ++t) u[t] = pkbf(sv[2 * t], sv[2 * t + 1]);
        const bf16x8 bf = __builtin_bit_cast(bf16x8, u);
#pragma unroll
        for (int pt = 0; pt < 2; ++pt)
          acc2[pt] = __builtin_amdgcn_mfma_f32_16x16x32_bf16(w2f[pt][s], bf, acc2[pt], 0, 0, 0);
      }

      float* op = out2 + (rowI * NN + j) * P2;
#pragma unroll
      for (int pt = 0; pt < 2; ++pt) {
        f32x4 o;
#pragma unroll
        for (int r = 0; r < 4; ++r) o[r] = sigm(acc2[pt][r]);
        *(f32x4*)(op + 16 * pt + 4 * bq) = o;
      }
    }

    // ---- MIRROR: out(j,i); in = [f2, f3, f0, f1] (pure-register compute) ----
    {
      f32x4 acc[8];
#pragma unroll
      for (int th = 0; th < 8; ++th) {
        const f32x4 bi = *(const f32x4*)&lb1[16 * th + 4 * bq];
        acc[th] = __builtin_amdgcn_mfma_f32_16x16x32_bf16(wl[(0 + th) * 64 + lane], f2, bi, 0, 0, 0);
      }
#pragma unroll
      for (int th = 0; th < 8; ++th)
        acc[th] = __builtin_amdgcn_mfma_f32_16x16x32_bf16(wl[(8 + th) * 64 + lane], f3, acc[th], 0, 0, 0);
#pragma unroll
      for (int th = 0; th < 8; ++th)
        acc[th] = __builtin_amdgcn_mfma_f32_16x16x32_bf16(wl[(16 + th) * 64 + lane], f0, acc[th], 0, 0, 0);
#pragma unroll
      for (int th = 0; th < 8; ++th)
        acc[th] = __builtin_amdgcn_mfma_f32_16x16x32_bf16(wl[(24 + th) * 64 + lane], f1, acc[th], 0, 0, 0);

      f32x4 acc2[2];
#pragma unroll
      for (int pt = 0; pt < 2; ++pt) acc2[pt] = bias2[pt];
#pragma unroll
      for (int s = 0; s < 4; ++s) {
        float sv[8];
#pragma unroll
        for (int e = 0; e < 4; ++e) {
          sv[e] = sigm(acc[2 * s][e]);
          sv[4 + e] = sigm(acc[2 * s + 1][e]);
        }
        u32x4 u;
#pragma unroll
        for (int t = 0; t < 4; ++t) u[t] = pkbf(sv[2 * t], sv[2 * t + 1]);
        const bf16x8 bf = __builtin_bit_cast(bf16x8, u);
#pragma unroll
        for (int pt = 0; pt < 2; ++pt)
          acc2[pt] = __builtin_amdgcn_mfma_f32_16x16x32_bf16(w2f[pt][s], bf, acc2[pt], 0, 0, 0);
      }

      float* op = out2 + (((size_t)b * NN + j) * NN + i) * P2;
#pragma unroll
      for (int pt = 0; pt < 2; ++pt) {
        f32x4 o;
#pragma unroll
        for (int r = 0; r < 4; ++r) o[r] = sigm(acc2[pt][r]);
        *(f32x4*)(op + 16 * pt + 4 * bq) = o;
      }
    }
  }

  // ---- Complete the reduction in LDS ----
#pragma unroll
  for (int msk = 1; msk < 16; msk <<= 1) {
#pragma unroll
    for (int r = 0; r < 4; ++r) {
      pmx0[r] = fmaxf(pmx0[r], __shfl_xor(pmx0[r], msk));
      pmx1[r] = fmaxf(pmx1[r], __shfl_xor(pmx1[r], msk));
      pmn0[r] = fminf(pmn0[r], __shfl_xor(pmn0[r], msk));
      pmn1[r] = fminf(pmn1[r], __shfl_xor(pmn1[r], msk));
    }
  }
  if (m == 0) {
#pragma unroll
    for (int r = 0; r < 4; ++r) {
      pm[wv][4 * bq + r] = pmx0[r];  pm[wv][16 + 4 * bq + r] = pmx1[r];
      pn[wv][4 * bq + r] = pmn0[r];  pn[wv][16 + 4 * bq + r] = pmn1[r];
    }
  }
  // Fill diagonal-MLP input while the reduction partials settle.
  if (tid >= 64 && tid < 128) {
    const int q = tid - 64;
    const float v = (q < 32) ? x2[(rowI * NN + i) * P2 + q] : x1bi[q - 32];
    in2[q] = v;
    in2[64 + q] = v;
  }
  __syncthreads();

  // ---- Fused tail: arity-1 MLP input assembly ----
  if (tid < 32) {
    float a = pm[0][tid], c = pn[0][tid];
#pragma unroll
    for (int g = 1; g < 8; ++g) {
      a = fmaxf(a, pm[g][tid]);
      c = fminf(c, pn[g][tid]);
    }
    in1[tid] = x1bi[tid];
    in1[48 + tid] = a;
    in1[80 + tid] = c;
  } else if (tid < 48) {
    in1[tid] = x0[b * P0 + (tid - 32)];
  }
  __syncthreads();

  // Hidden layers: tid<128 -> arity-1 (112 in), 128<=tid<256 -> diag (128 in).
  if (tid < 128) {
    float s = b1_1[tid];
    for (int k = 0; k < 112; ++k) s += in1[k] * W1_1[k * HH + tid];
    hid1[tid] = sigm(s);
  } else if (tid < 256) {
    const int h = tid - 128;
    float s = lb1[h];
    for (int k = 0; k < 128; ++k) s += in2[k] * W1[k * HH + h];
    hid2[h] = sigm(s);
  }
  __syncthreads();

  // Output layers.
  if (tid < 32) {
    float s = b2_1[tid];
    for (int k = 0; k < 128; ++k) s += hid1[k] * W2_1[k * P1 + tid];
    out1[rowI * P1 + tid] = sigm(s);
  } else if (tid >= 128 && tid < 160) {
    const int p = tid - 128;
    float s = b2[p];
    for (int k = 0; k < 128; ++k) s += hid2[k] * W2[k * P2 + p];
    out2[(rowI * NN + i) * P2 + p] = sigm(s);
  }
}

// ---------------------------------------------------------------------------
// Arity-0
// ---------------------------------------------------------------------------
__global__ __launch_bounds__(256) void k_arity0(
    const float* __restrict__ x0, const float* __restrict__ x1,
    const float* __restrict__ W1, const float* __restrict__ b1,
    const float* __restrict__ W2, const float* __restrict__ b2,
    float* __restrict__ out0) {
  __shared__ float rmx[8][32], rmn[8][32];
  __shared__ float in0[80];
  __shared__ float hid[128];

  const int tid = threadIdx.x;
  const int b = blockIdx.x;  // 0..1
  const int p = tid & 31, jg = tid >> 5;

  float mx = -1e30f, mn = 1e30f;
  for (int j = jg; j < NN; j += 8) {
    const float v = x1[((size_t)b * NN + j) * P1 + p];
    mx = fmaxf(mx, v);
    mn = fminf(mn, v);
  }
  rmx[jg][p] = mx;
  rmn[jg][p] = mn;
  __syncthreads();

  if (tid < 32) {
    float a = rmx[0][tid], c = rmn[0][tid];
#pragma unroll
    for (int g = 1; g < 8; ++g) {
      a = fmaxf(a, rmx[g][tid]);
      c = fminf(c, rmn[g][tid]);
    }
    in0[16 + tid] = a;
    in0[48 + tid] = c;
  } else if (tid < 48) {
    in0[tid - 32] = x0[b * P0 + (tid - 32)];
  }
  __syncthreads();

  if (tid < 128) {
    float s = b1[tid];
    for (int k = 0; k < 80; ++k) s += in0[k] * W1[k * HH + tid];
    hid[tid] = sigm(s);
  }
  __syncthreads();

  if (tid < 16) {
    float s = b2[tid];
    for (int k = 0; k < 128; ++k) s += hid[k] * W2[k * P0 + tid];
    out0[b * P0 + tid] = sigm(s);
  }
}

extern "C" void kernel_launch(void* const* d_in, const int* in_sizes, int n_in,
                              void* d_out, int out_size, void* d_ws, size_t ws_size,
                              hipStream_t stream) {
  const float* x0   = (const float*)d_in[0];
  const float* x1   = (const float*)d_in[1];
  const float* x2   = (const float*)d_in[2];
  const float* W1_0 = (const float*)d_in[3];
  const float* b1_0 = (const float*)d_in[4];
  const float* W2_0 = (const float*)d_in[5];
  const float* b2_0 = (const float*)d_in[6];
  const float* W1_1 = (const float*)d_in[7];
  const float* b1_1 = (const float*)d_in[8];
  const float* W2_1 = (const float*)d_in[9];
  const float* b2_1 = (const float*)d_in[10];
  const float* W1_2 = (const float*)d_in[11];
  const float* b1_2 = (const float*)d_in[12];
  const float* W2_2 = (const float*)d_in[13];
  const float* b2_2 = (const float*)d_in[14];

  float* out0 = (float*)d_out;
  float* out1 = out0 + (size_t)BB * P0;
  float* out2 = out1 + (size_t)BB * NN * P1;

  hipLaunchKernelGGL(k_arity2, dim3(1024), dim3(512), 0, stream,
                     x0, x1, x2, W1_2, b1_2, W2_2, b2_2,
                     W1_1, b1_1, W2_1, b2_1, out1, out2);
  hipLaunchKernelGGL(k_arity0, dim3(2), dim3(256), 0, stream,
                     x0, x1, W1_0, b1_0, W2_0, b2_0, out0);
}

// Round 14
// 75.854 us; speedup vs baseline: 1.5056x; 1.5056x over previous
//
#include <hip/hip_runtime.h>
#include <hip/hip_bf16.h>

// Problem constants
#define BB 2
#define NN 512
#define P0 16
#define P1 32
#define P2 32
#define HH 128

typedef __attribute__((ext_vector_type(8))) short bf16x8;
typedef __attribute__((ext_vector_type(4))) float f32x4;
typedef __attribute__((ext_vector_type(4))) unsigned u32x4;

__device__ __forceinline__ unsigned pkbf(float lo, float hi) {
  __hip_bfloat162 h = __float22bfloat162_rn(float2{lo, hi});
  unsigned r;
  __builtin_memcpy(&r, &h, 4);
  return r;
}

__device__ __forceinline__ float sigm(float x) {
  return __builtin_amdgcn_rcpf(1.0f + __expf(-x));
}

__device__ __forceinline__ bf16x8 pack2(f32x4 a, f32x4 b) {
  u32x4 u;
  u[0] = pkbf(a[0], a[1]);
  u[1] = pkbf(a[2], a[3]);
  u[2] = pkbf(b[0], b[1]);
  u[3] = pkbf(b[2], b[3]);
  return __builtin_bit_cast(bf16x8, u);
}

// ---------------------------------------------------------------------------
// Single fused kernel, grid 1026 x 256:
//  blocks 0..1023  : round-12 structure (best: 76us) — PAIRED arity-2 over
//                    ring j=i+1..i+256 (out(i,j) AND out(j,i) per pair),
//                    complete in-block arity-1 reduction, fused tail
//                    (arity-1 MLP + diagonal). 4 waves x 4 iters (the mapped
//                    optimum: round 13's 8 waves x 2 iters was -35%).
//  blocks 1024..1025: arity-0 (one per b), reusing the same LDS.
//  NEW: s_setprio(1) around GEMM1 MFMA clusters (independent-wave regime,
//  attn-like => expected +0-7%; lockstep-GEMM null result doesn't apply).
// NOTE: plain __launch_bounds__(256) — (256,4) caused 64-VGPR scratch spill.
// ---------------------------------------------------------------------------
__global__ __launch_bounds__(256) void k_fused(
    const float* __restrict__ x0, const float* __restrict__ x1,
    const float* __restrict__ x2,
    const float* __restrict__ W1, const float* __restrict__ b1,
    const float* __restrict__ W2, const float* __restrict__ b2,
    const float* __restrict__ W1_1, const float* __restrict__ b1_1,
    const float* __restrict__ W2_1, const float* __restrict__ b2_1,
    const float* __restrict__ W1_0, const float* __restrict__ b1_0,
    const float* __restrict__ W2_0, const float* __restrict__ b2_0,
    float* __restrict__ out0, float* __restrict__ out1,
    float* __restrict__ out2) {
  __shared__ __align__(16) short lw[32 * 64 * 8];  // W1 frags: 32 KiB
  __shared__ float pm[8][32], pn[8][32];           // partials (arity0 reuses)
  __shared__ float in1[112], in2[128];             // tail MLP inputs
  __shared__ float hid1[HH], hid2[HH];             // tail hidden layers

  const int tid = threadIdx.x;
  const int bid = blockIdx.x;

  // ======================= arity-0 path (blocks 1024..1025) ================
  if (bid >= 1024) {
    const int b = bid - 1024;  // 0..1
    const int p = tid & 31, jg = tid >> 5;

    float mx = -1e30f, mn = 1e30f;
    for (int j = jg; j < NN; j += 8) {
      const float v = x1[((size_t)b * NN + j) * P1 + p];
      mx = fmaxf(mx, v);
      mn = fminf(mn, v);
    }
    pm[jg][p] = mx;
    pn[jg][p] = mn;
    __syncthreads();

    if (tid < 32) {
      float a = pm[0][tid], c = pn[0][tid];
#pragma unroll
      for (int g = 1; g < 8; ++g) {
        a = fmaxf(a, pm[g][tid]);
        c = fminf(c, pn[g][tid]);
      }
      in1[16 + tid] = a;
      in1[48 + tid] = c;
    } else if (tid < 48) {
      in1[tid - 32] = x0[b * P0 + (tid - 32)];
    }
    __syncthreads();

    if (tid < 128) {
      float s = b1_0[tid];
      for (int k = 0; k < 80; ++k) s += in1[k] * W1_0[k * HH + tid];
      hid1[tid] = sigm(s);
    }
    __syncthreads();

    if (tid < 16) {
      float s = b2_0[tid];
      for (int k = 0; k < 128; ++k) s += hid1[k] * W2_0[k * P0 + tid];
      out0[b * P0 + tid] = sigm(s);
    }
    return;
  }

  // ======================= arity-2 paired path (blocks 0..1023) ============
  const int b = bid >> 9;   // 0..1
  const int i = bid & 511;  // 0..511

  // Stage W1 fragments to LDS (pre-swizzled to MFMA fragment order).
  for (int c = tid; c < 2048; c += 256) {
    const int l = c & 63, th = (c >> 6) & 7, s = c >> 9;
    const int fm = l & 15, fb = l >> 4;
    const int h = 16 * th + fm;
    float v[8];
#pragma unroll
    for (int e = 0; e < 8; ++e) {
      const int k = 32 * s + 4 * fb + (e & 3) + 16 * (e >> 2);
      v[e] = W1[k * HH + h];
    }
    unsigned* dst = (unsigned*)&lw[c * 8];
#pragma unroll
    for (int t = 0; t < 4; ++t) dst[t] = pkbf(v[2 * t], v[2 * t + 1]);
  }

  const int lane = tid & 63;
  const int wv = tid >> 6;
  const int m = lane & 15, bq = lane >> 4;

  // W2^T fragments in registers: A2[p][h], p = 16*pt + m
  bf16x8 w2f[2][4];
#pragma unroll
  for (int pt = 0; pt < 2; ++pt) {
#pragma unroll
    for (int s = 0; s < 4; ++s) {
      const int p = 16 * pt + m;
      float v[8];
#pragma unroll
      for (int e = 0; e < 8; ++e) {
        const int h = 32 * s + 4 * bq + (e & 3) + 16 * (e >> 2);
        v[e] = W2[h * P2 + p];
      }
      u32x4 u;
#pragma unroll
      for (int t = 0; t < 4; ++t) u[t] = pkbf(v[2 * t], v[2 * t + 1]);
      w2f[pt][s] = __builtin_bit_cast(bf16x8, u);
    }
  }

  f32x4 bias1[8];
#pragma unroll
  for (int th = 0; th < 8; ++th)
#pragma unroll
    for (int r = 0; r < 4; ++r) bias1[th][r] = b1[16 * th + 4 * bq + r];
  f32x4 bias2[2];
#pragma unroll
  for (int pt = 0; pt < 2; ++pt)
#pragma unroll
    for (int r = 0; r < 4; ++r) bias2[pt][r] = b2[16 * pt + 4 * bq + r];

  // x1[b,i,:] fragment, constant over the block
  const float* x1bi = x1 + ((size_t)b * NN + i) * P1;
  const bf16x8 f1 = pack2(*(const f32x4*)(x1bi + 4 * bq),
                          *(const f32x4*)(x1bi + 16 + 4 * bq));

  __syncthreads();

  const bf16x8* wl = (const bf16x8*)lw;
  const size_t rowI = (size_t)b * NN + i;

  // Fused arity-1 reduction partials (channels 4bq..4bq+3 and 16+4bq..).
  f32x4 pmx0 = {0.f, 0.f, 0.f, 0.f}, pmx1 = {0.f, 0.f, 0.f, 0.f};
  f32x4 pmn0 = {1.f, 1.f, 1.f, 1.f}, pmn1 = {1.f, 1.f, 1.f, 1.f};

#pragma unroll
  for (int it = 0; it < 4; ++it) {
    const int j = (i + 1 + it * 64 + wv * 16 + m) & 511;
    const int j2 = (j + 256) & 511;  // other-half row for reduction only

    const float* p0 = x2 + (rowI * NN + j) * P2;                  // x2[b,i,j,:]
    const float* p2 = x2 + (((size_t)b * NN + j) * NN + i) * P2;  // x2[b,j,i,:]
    const float* p3 = x1 + ((size_t)b * NN + j) * P1;             // x1[b,j,:]
    const float* p4 = x2 + (rowI * NN + j2) * P2;                 // x2[b,i,j2,:]
    const f32x4 c0a = *(const f32x4*)(p0 + 4 * bq), c0b = *(const f32x4*)(p0 + 16 + 4 * bq);
    const f32x4 c2a = *(const f32x4*)(p2 + 4 * bq), c2b = *(const f32x4*)(p2 + 16 + 4 * bq);
    const f32x4 c3a = *(const f32x4*)(p3 + 4 * bq), c3b = *(const f32x4*)(p3 + 16 + 4 * bq);
    const f32x4 c4a = *(const f32x4*)(p4 + 4 * bq), c4b = *(const f32x4*)(p4 + 16 + 4 * bq);

    // Reduction: c0 (ring j, never diagonal) unconditional; c4 masked at j2==i.
    {
      const bool dg = (j2 == i);
#pragma unroll
      for (int r = 0; r < 4; ++r) {
        pmx0[r] = fmaxf(pmx0[r], fmaxf(c0a[r], dg ? 0.0f : c4a[r]));
        pmx1[r] = fmaxf(pmx1[r], fmaxf(c0b[r], dg ? 0.0f : c4b[r]));
        pmn0[r] = fminf(pmn0[r], fminf(c0a[r], dg ? 1.0f : c4a[r]));
        pmn1[r] = fminf(pmn1[r], fminf(c0b[r], dg ? 1.0f : c4b[r]));
      }
    }

    const bf16x8 f0 = pack2(c0a, c0b);
    const bf16x8 f2 = pack2(c2a, c2b);
    const bf16x8 f3 = pack2(c3a, c3b);

    // ---- DIRECT: out(i,j); in = [f0, f1, f2, f3] ----
    {
      f32x4 acc[8];
      __builtin_amdgcn_s_setprio(1);
#pragma unroll
      for (int th = 0; th < 8; ++th)
        acc[th] = __builtin_amdgcn_mfma_f32_16x16x32_bf16(wl[(0 + th) * 64 + lane], f0, bias1[th], 0, 0, 0);
#pragma unroll
      for (int th = 0; th < 8; ++th)
        acc[th] = __builtin_amdgcn_mfma_f32_16x16x32_bf16(wl[(8 + th) * 64 + lane], f1, acc[th], 0, 0, 0);
#pragma unroll
      for (int th = 0; th < 8; ++th)
        acc[th] = __builtin_amdgcn_mfma_f32_16x16x32_bf16(wl[(16 + th) * 64 + lane], f2, acc[th], 0, 0, 0);
#pragma unroll
      for (int th = 0; th < 8; ++th)
        acc[th] = __builtin_amdgcn_mfma_f32_16x16x32_bf16(wl[(24 + th) * 64 + lane], f3, acc[th], 0, 0, 0);
      __builtin_amdgcn_s_setprio(0);

      f32x4 acc2[2];
#pragma unroll
      for (int pt = 0; pt < 2; ++pt) acc2[pt] = bias2[pt];
#pragma unroll
      for (int s = 0; s < 4; ++s) {
        float sv[8];
#pragma unroll
        for (int e = 0; e < 4; ++e) {
          sv[e] = sigm(acc[2 * s][e]);
          sv[4 + e] = sigm(acc[2 * s + 1][e]);
        }
        u32x4 u;
#pragma unroll
        for (int t = 0; t < 4; ++t) u[t] = pkbf(sv[2 * t], sv[2 * t + 1]);
        const bf16x8 bf = __builtin_bit_cast(bf16x8, u);
#pragma unroll
        for (int pt = 0; pt < 2; ++pt)
          acc2[pt] = __builtin_amdgcn_mfma_f32_16x16x32_bf16(w2f[pt][s], bf, acc2[pt], 0, 0, 0);
      }

      float* op = out2 + (rowI * NN + j) * P2;
#pragma unroll
      for (int pt = 0; pt < 2; ++pt) {
        f32x4 o;
#pragma unroll
        for (int r = 0; r < 4; ++r) o[r] = sigm(acc2[pt][r]);
        *(f32x4*)(op + 16 * pt + 4 * bq) = o;
      }
    }

    // ---- MIRROR: out(j,i); in = [f2, f3, f0, f1] (pure-register compute) ----
    {
      f32x4 acc[8];
      __builtin_amdgcn_s_setprio(1);
#pragma unroll
      for (int th = 0; th < 8; ++th)
        acc[th] = __builtin_amdgcn_mfma_f32_16x16x32_bf16(wl[(0 + th) * 64 + lane], f2, bias1[th], 0, 0, 0);
#pragma unroll
      for (int th = 0; th < 8; ++th)
        acc[th] = __builtin_amdgcn_mfma_f32_16x16x32_bf16(wl[(8 + th) * 64 + lane], f3, acc[th], 0, 0, 0);
#pragma unroll
      for (int th = 0; th < 8; ++th)
        acc[th] = __builtin_amdgcn_mfma_f32_16x16x32_bf16(wl[(16 + th) * 64 + lane], f0, acc[th], 0, 0, 0);
#pragma unroll
      for (int th = 0; th < 8; ++th)
        acc[th] = __builtin_amdgcn_mfma_f32_16x16x32_bf16(wl[(24 + th) * 64 + lane], f1, acc[th], 0, 0, 0);
      __builtin_amdgcn_s_setprio(0);

      f32x4 acc2[2];
#pragma unroll
      for (int pt = 0; pt < 2; ++pt) acc2[pt] = bias2[pt];
#pragma unroll
      for (int s = 0; s < 4; ++s) {
        float sv[8];
#pragma unroll
        for (int e = 0; e < 4; ++e) {
          sv[e] = sigm(acc[2 * s][e]);
          sv[4 + e] = sigm(acc[2 * s + 1][e]);
        }
        u32x4 u;
#pragma unroll
        for (int t = 0; t < 4; ++t) u[t] = pkbf(sv[2 * t], sv[2 * t + 1]);
        const bf16x8 bf = __builtin_bit_cast(bf16x8, u);
#pragma unroll
        for (int pt = 0; pt < 2; ++pt)
          acc2[pt] = __builtin_amdgcn_mfma_f32_16x16x32_bf16(w2f[pt][s], bf, acc2[pt], 0, 0, 0);
      }

      float* op = out2 + (((size_t)b * NN + j) * NN + i) * P2;
#pragma unroll
      for (int pt = 0; pt < 2; ++pt) {
        f32x4 o;
#pragma unroll
        for (int r = 0; r < 4; ++r) o[r] = sigm(acc2[pt][r]);
        *(f32x4*)(op + 16 * pt + 4 * bq) = o;
      }
    }
  }

  // ---- Complete the reduction in LDS ----
#pragma unroll
  for (int msk = 1; msk < 16; msk <<= 1) {
#pragma unroll
    for (int r = 0; r < 4; ++r) {
      pmx0[r] = fmaxf(pmx0[r], __shfl_xor(pmx0[r], msk));
      pmx1[r] = fmaxf(pmx1[r], __shfl_xor(pmx1[r], msk));
      pmn0[r] = fminf(pmn0[r], __shfl_xor(pmn0[r], msk));
      pmn1[r] = fminf(pmn1[r], __shfl_xor(pmn1[r], msk));
    }
  }
  if (m == 0) {
#pragma unroll
    for (int r = 0; r < 4; ++r) {
      pm[wv][4 * bq + r] = pmx0[r];  pm[wv][16 + 4 * bq + r] = pmx1[r];
      pn[wv][4 * bq + r] = pmn0[r];  pn[wv][16 + 4 * bq + r] = pmn1[r];
    }
  }
  // Fill diagonal-MLP input while the reduction partials settle.
  if (tid >= 64 && tid < 128) {
    const int q = tid - 64;
    const float v = (q < 32) ? x2[(rowI * NN + i) * P2 + q] : x1bi[q - 32];
    in2[q] = v;
    in2[64 + q] = v;
  }
  __syncthreads();

  // ---- Fused tail: arity-1 MLP input assembly ----
  if (tid < 32) {
    float a = pm[0][tid], c = pn[0][tid];
#pragma unroll
    for (int g = 1; g < 4; ++g) {
      a = fmaxf(a, pm[g][tid]);
      c = fminf(c, pn[g][tid]);
    }
    in1[tid] = x1bi[tid];
    in1[48 + tid] = a;
    in1[80 + tid] = c;
  } else if (tid < 48) {
    in1[tid] = x0[b * P0 + (tid - 32)];
  }
  __syncthreads();

  // Hidden layers: tid<128 -> arity-1 (112 in), tid>=128 -> diagonal (128 in).
  if (tid < 128) {
    float s = b1_1[tid];
    for (int k = 0; k < 112; ++k) s += in1[k] * W1_1[k * HH + tid];
    hid1[tid] = sigm(s);
  } else {
    const int h = tid - 128;
    float s = b1[h];
    for (int k = 0; k < 128; ++k) s += in2[k] * W1[k * HH + h];
    hid2[h] = sigm(s);
  }
  __syncthreads();

  // Output layers.
  if (tid < 32) {
    float s = b2_1[tid];
    for (int k = 0; k < 128; ++k) s += hid1[k] * W2_1[k * P1 + tid];
    out1[rowI * P1 + tid] = sigm(s);
  } else if (tid >= 128 && tid < 160) {
    const int p = tid - 128;
    float s = b2[p];
    for (int k = 0; k < 128; ++k) s += hid2[k] * W2[k * P2 + p];
    out2[(rowI * NN + i) * P2 + p] = sigm(s);
  }
}

extern "C" void kernel_launch(void* const* d_in, const int* in_sizes, int n_in,
                              void* d_out, int out_size, void* d_ws, size_t ws_size,
                              hipStream_t stream) {
  const float* x0   = (const float*)d_in[0];
  const float* x1   = (const float*)d_in[1];
  const float* x2   = (const float*)d_in[2];
  const float* W1_0 = (const float*)d_in[3];
  const float* b1_0 = (const float*)d_in[4];
  const float* W2_0 = (const float*)d_in[5];
  const float* b2_0 = (const float*)d_in[6];
  const float* W1_1 = (const float*)d_in[7];
  const float* b1_1 = (const float*)d_in[8];
  const float* W2_1 = (const float*)d_in[9];
  const float* b2_1 = (const float*)d_in[10];
  const float* W1_2 = (const float*)d_in[11];
  const float* b1_2 = (const float*)d_in[12];
  const float* W2_2 = (const float*)d_in[13];
  const float* b2_2 = (const float*)d_in[14];

  float* out0 = (float*)d_out;
  float* out1 = out0 + (size_t)BB * P0;
  float* out2 = out1 + (size_t)BB * NN * P1;

  hipLaunchKernelGGL(k_fused, dim3(1026), dim3(256), 0, stream,
                     x0, x1, x2, W1_2, b1_2, W2_2, b2_2,
                     W1_1, b1_1, W2_1, b2_1,
                     W1_0, b1_0, W2_0, b2_0,
                     out0, out1, out2);
}

// Round 15
// 73.704 us; speedup vs baseline: 1.5495x; 1.0292x over previous
//
#include <hip/hip_runtime.h>
#include <hip/hip_bf16.h>

// Problem constants
#define BB 2
#define NN 512
#define P0 16
#define P1 32
#define P2 32
#define HH 128

typedef __attribute__((ext_vector_type(8))) short bf16x8;
typedef __attribute__((ext_vector_type(4))) float f32x4;
typedef __attribute__((ext_vector_type(4))) unsigned u32x4;

__device__ __forceinline__ unsigned pkbf(float lo, float hi) {
  __hip_bfloat162 h = __float22bfloat162_rn(float2{lo, hi});
  unsigned r;
  __builtin_memcpy(&r, &h, 4);
  return r;
}

__device__ __forceinline__ float sigm(float x) {
  return __builtin_amdgcn_rcpf(1.0f + __expf(-x));
}

__device__ __forceinline__ bf16x8 pack2(f32x4 a, f32x4 b) {
  u32x4 u;
  u[0] = pkbf(a[0], a[1]);
  u[1] = pkbf(a[2], a[3]);
  u[2] = pkbf(b[0], b[1]);
  u[3] = pkbf(b[2], b[3]);
  return __builtin_bit_cast(bf16x8, u);
}

// ---------------------------------------------------------------------------
// Single fused kernel, grid 1026 x 256 (round-14 best: 75.9us).
// THIS ROUND: dual-pipeline the pair. Both GEMM1s (direct out(i,j) and mirror
// out(j,i)) keep accumulators live simultaneously (64-MFMA burst), and the two
// sigmoid+GEMM2 phases interleave s-step-wise — MFMA(mirror) overlaps
// trans(direct). Funded by bias1 -> LDS broadcast (verified round 13).
// setprio removed (round 14: neutral in timed run).
// NOTE: plain __launch_bounds__(256) — (256,4) caused 64-VGPR scratch spill.
// ---------------------------------------------------------------------------
__global__ __launch_bounds__(256) void k_fused(
    const float* __restrict__ x0, const float* __restrict__ x1,
    const float* __restrict__ x2,
    const float* __restrict__ W1, const float* __restrict__ b1,
    const float* __restrict__ W2, const float* __restrict__ b2,
    const float* __restrict__ W1_1, const float* __restrict__ b1_1,
    const float* __restrict__ W2_1, const float* __restrict__ b2_1,
    const float* __restrict__ W1_0, const float* __restrict__ b1_0,
    const float* __restrict__ W2_0, const float* __restrict__ b2_0,
    float* __restrict__ out0, float* __restrict__ out1,
    float* __restrict__ out2) {
  __shared__ __align__(16) short lw[32 * 64 * 8];  // W1 frags: 32 KiB
  __shared__ __align__(16) float lb1[HH];          // bias1 broadcast
  __shared__ float pm[8][32], pn[8][32];           // partials (arity0 reuses)
  __shared__ float in1[112], in2[128];             // tail MLP inputs
  __shared__ float hid1[HH], hid2[HH];             // tail hidden layers

  const int tid = threadIdx.x;
  const int bid = blockIdx.x;

  // ======================= arity-0 path (blocks 1024..1025) ================
  if (bid >= 1024) {
    const int b = bid - 1024;  // 0..1
    const int p = tid & 31, jg = tid >> 5;

    float mx = -1e30f, mn = 1e30f;
    for (int j = jg; j < NN; j += 8) {
      const float v = x1[((size_t)b * NN + j) * P1 + p];
      mx = fmaxf(mx, v);
      mn = fminf(mn, v);
    }
    pm[jg][p] = mx;
    pn[jg][p] = mn;
    __syncthreads();

    if (tid < 32) {
      float a = pm[0][tid], c = pn[0][tid];
#pragma unroll
      for (int g = 1; g < 8; ++g) {
        a = fmaxf(a, pm[g][tid]);
        c = fminf(c, pn[g][tid]);
      }
      in1[16 + tid] = a;
      in1[48 + tid] = c;
    } else if (tid < 48) {
      in1[tid - 32] = x0[b * P0 + (tid - 32)];
    }
    __syncthreads();

    if (tid < 128) {
      float s = b1_0[tid];
      for (int k = 0; k < 80; ++k) s += in1[k] * W1_0[k * HH + tid];
      hid1[tid] = sigm(s);
    }
    __syncthreads();

    if (tid < 16) {
      float s = b2_0[tid];
      for (int k = 0; k < 128; ++k) s += hid1[k] * W2_0[k * P0 + tid];
      out0[b * P0 + tid] = sigm(s);
    }
    return;
  }

  // ======================= arity-2 paired path (blocks 0..1023) ============
  const int b = bid >> 9;   // 0..1
  const int i = bid & 511;  // 0..511

  // Stage W1 fragments to LDS (pre-swizzled to MFMA fragment order).
  for (int c = tid; c < 2048; c += 256) {
    const int l = c & 63, th = (c >> 6) & 7, s = c >> 9;
    const int fm = l & 15, fb = l >> 4;
    const int h = 16 * th + fm;
    float v[8];
#pragma unroll
    for (int e = 0; e < 8; ++e) {
      const int k = 32 * s + 4 * fb + (e & 3) + 16 * (e >> 2);
      v[e] = W1[k * HH + h];
    }
    unsigned* dst = (unsigned*)&lw[c * 8];
#pragma unroll
    for (int t = 0; t < 4; ++t) dst[t] = pkbf(v[2 * t], v[2 * t + 1]);
  }
  if (tid < HH) lb1[tid] = b1[tid];

  const int lane = tid & 63;
  const int wv = tid >> 6;
  const int m = lane & 15, bq = lane >> 4;

  // W2^T fragments in registers: A2[p][h], p = 16*pt + m
  bf16x8 w2f[2][4];
#pragma unroll
  for (int pt = 0; pt < 2; ++pt) {
#pragma unroll
    for (int s = 0; s < 4; ++s) {
      const int p = 16 * pt + m;
      float v[8];
#pragma unroll
      for (int e = 0; e < 8; ++e) {
        const int h = 32 * s + 4 * bq + (e & 3) + 16 * (e >> 2);
        v[e] = W2[h * P2 + p];
      }
      u32x4 u;
#pragma unroll
      for (int t = 0; t < 4; ++t) u[t] = pkbf(v[2 * t], v[2 * t + 1]);
      w2f[pt][s] = __builtin_bit_cast(bf16x8, u);
    }
  }

  f32x4 bias2[2];
#pragma unroll
  for (int pt = 0; pt < 2; ++pt)
#pragma unroll
    for (int r = 0; r < 4; ++r) bias2[pt][r] = b2[16 * pt + 4 * bq + r];

  // x1[b,i,:] fragment, constant over the block
  const float* x1bi = x1 + ((size_t)b * NN + i) * P1;
  const bf16x8 f1 = pack2(*(const f32x4*)(x1bi + 4 * bq),
                          *(const f32x4*)(x1bi + 16 + 4 * bq));

  __syncthreads();

  const bf16x8* wl = (const bf16x8*)lw;
  const size_t rowI = (size_t)b * NN + i;

  // Fused arity-1 reduction partials (channels 4bq..4bq+3 and 16+4bq..).
  f32x4 pmx0 = {0.f, 0.f, 0.f, 0.f}, pmx1 = {0.f, 0.f, 0.f, 0.f};
  f32x4 pmn0 = {1.f, 1.f, 1.f, 1.f}, pmn1 = {1.f, 1.f, 1.f, 1.f};

#pragma unroll
  for (int it = 0; it < 4; ++it) {
    const int j = (i + 1 + it * 64 + wv * 16 + m) & 511;
    const int j2 = (j + 256) & 511;  // other-half row for reduction only

    const float* p0 = x2 + (rowI * NN + j) * P2;                  // x2[b,i,j,:]
    const float* p2 = x2 + (((size_t)b * NN + j) * NN + i) * P2;  // x2[b,j,i,:]
    const float* p3 = x1 + ((size_t)b * NN + j) * P1;             // x1[b,j,:]
    const float* p4 = x2 + (rowI * NN + j2) * P2;                 // x2[b,i,j2,:]
    const f32x4 c0a = *(const f32x4*)(p0 + 4 * bq), c0b = *(const f32x4*)(p0 + 16 + 4 * bq);
    const f32x4 c2a = *(const f32x4*)(p2 + 4 * bq), c2b = *(const f32x4*)(p2 + 16 + 4 * bq);
    const f32x4 c3a = *(const f32x4*)(p3 + 4 * bq), c3b = *(const f32x4*)(p3 + 16 + 4 * bq);
    const f32x4 c4a = *(const f32x4*)(p4 + 4 * bq), c4b = *(const f32x4*)(p4 + 16 + 4 * bq);

    // Reduction: c0 (ring j, never diagonal) unconditional; c4 masked at j2==i.
    {
      const bool dg = (j2 == i);
#pragma unroll
      for (int r = 0; r < 4; ++r) {
        pmx0[r] = fmaxf(pmx0[r], fmaxf(c0a[r], dg ? 0.0f : c4a[r]));
        pmx1[r] = fmaxf(pmx1[r], fmaxf(c0b[r], dg ? 0.0f : c4b[r]));
        pmn0[r] = fminf(pmn0[r], fminf(c0a[r], dg ? 1.0f : c4a[r]));
        pmn1[r] = fminf(pmn1[r], fminf(c0b[r], dg ? 1.0f : c4b[r]));
      }
    }

    const bf16x8 f0 = pack2(c0a, c0b);
    const bf16x8 f2 = pack2(c2a, c2b);
    const bf16x8 f3 = pack2(c3a, c3b);

    // ---- Dual GEMM1 burst: direct (f0,f1,f2,f3) and mirror (f2,f3,f0,f1) ----
    f32x4 accD[8], accM[8];
#pragma unroll
    for (int th = 0; th < 8; ++th) {
      const f32x4 bi = *(const f32x4*)&lb1[16 * th + 4 * bq];
      accD[th] = __builtin_amdgcn_mfma_f32_16x16x32_bf16(wl[(0 + th) * 64 + lane], f0, bi, 0, 0, 0);
      accM[th] = __builtin_amdgcn_mfma_f32_16x16x32_bf16(wl[(0 + th) * 64 + lane], f2, bi, 0, 0, 0);
    }
#pragma unroll
    for (int th = 0; th < 8; ++th) {
      accD[th] = __builtin_amdgcn_mfma_f32_16x16x32_bf16(wl[(8 + th) * 64 + lane], f1, accD[th], 0, 0, 0);
      accM[th] = __builtin_amdgcn_mfma_f32_16x16x32_bf16(wl[(8 + th) * 64 + lane], f3, accM[th], 0, 0, 0);
    }
#pragma unroll
    for (int th = 0; th < 8; ++th) {
      accD[th] = __builtin_amdgcn_mfma_f32_16x16x32_bf16(wl[(16 + th) * 64 + lane], f2, accD[th], 0, 0, 0);
      accM[th] = __builtin_amdgcn_mfma_f32_16x16x32_bf16(wl[(16 + th) * 64 + lane], f0, accM[th], 0, 0, 0);
    }
#pragma unroll
    for (int th = 0; th < 8; ++th) {
      accD[th] = __builtin_amdgcn_mfma_f32_16x16x32_bf16(wl[(24 + th) * 64 + lane], f3, accD[th], 0, 0, 0);
      accM[th] = __builtin_amdgcn_mfma_f32_16x16x32_bf16(wl[(24 + th) * 64 + lane], f1, accM[th], 0, 0, 0);
    }

    // ---- Dual GEMM2, s-step interleaved: MFMA(one) overlaps trans(other) ----
    f32x4 acc2D[2], acc2M[2];
#pragma unroll
    for (int pt = 0; pt < 2; ++pt) { acc2D[pt] = bias2[pt]; acc2M[pt] = bias2[pt]; }
#pragma unroll
    for (int s = 0; s < 4; ++s) {
      float svD[8], svM[8];
#pragma unroll
      for (int e = 0; e < 4; ++e) {
        svD[e] = sigm(accD[2 * s][e]);
        svD[4 + e] = sigm(accD[2 * s + 1][e]);
        svM[e] = sigm(accM[2 * s][e]);
        svM[4 + e] = sigm(accM[2 * s + 1][e]);
      }
      u32x4 uD, uM;
#pragma unroll
      for (int t = 0; t < 4; ++t) {
        uD[t] = pkbf(svD[2 * t], svD[2 * t + 1]);
        uM[t] = pkbf(svM[2 * t], svM[2 * t + 1]);
      }
      const bf16x8 bfD = __builtin_bit_cast(bf16x8, uD);
      const bf16x8 bfM = __builtin_bit_cast(bf16x8, uM);
#pragma unroll
      for (int pt = 0; pt < 2; ++pt) {
        acc2D[pt] = __builtin_amdgcn_mfma_f32_16x16x32_bf16(w2f[pt][s], bfD, acc2D[pt], 0, 0, 0);
        acc2M[pt] = __builtin_amdgcn_mfma_f32_16x16x32_bf16(w2f[pt][s], bfM, acc2M[pt], 0, 0, 0);
      }
    }

    // ---- Stores ----
    float* opD = out2 + (rowI * NN + j) * P2;
    float* opM = out2 + (((size_t)b * NN + j) * NN + i) * P2;
#pragma unroll
    for (int pt = 0; pt < 2; ++pt) {
      f32x4 oD, oM;
#pragma unroll
      for (int r = 0; r < 4; ++r) {
        oD[r] = sigm(acc2D[pt][r]);
        oM[r] = sigm(acc2M[pt][r]);
      }
      *(f32x4*)(opD + 16 * pt + 4 * bq) = oD;
      *(f32x4*)(opM + 16 * pt + 4 * bq) = oM;
    }
  }

  // ---- Complete the reduction in LDS ----
#pragma unroll
  for (int msk = 1; msk < 16; msk <<= 1) {
#pragma unroll
    for (int r = 0; r < 4; ++r) {
      pmx0[r] = fmaxf(pmx0[r], __shfl_xor(pmx0[r], msk));
      pmx1[r] = fmaxf(pmx1[r], __shfl_xor(pmx1[r], msk));
      pmn0[r] = fminf(pmn0[r], __shfl_xor(pmn0[r], msk));
      pmn1[r] = fminf(pmn1[r], __shfl_xor(pmn1[r], msk));
    }
  }
  if (m == 0) {
#pragma unroll
    for (int r = 0; r < 4; ++r) {
      pm[wv][4 * bq + r] = pmx0[r];  pm[wv][16 + 4 * bq + r] = pmx1[r];
      pn[wv][4 * bq + r] = pmn0[r];  pn[wv][16 + 4 * bq + r] = pmn1[r];
    }
  }
  // Fill diagonal-MLP input while the reduction partials settle.
  if (tid >= 64 && tid < 128) {
    const int q = tid - 64;
    const float v = (q < 32) ? x2[(rowI * NN + i) * P2 + q] : x1bi[q - 32];
    in2[q] = v;
    in2[64 + q] = v;
  }
  __syncthreads();

  // ---- Fused tail: arity-1 MLP input assembly ----
  if (tid < 32) {
    float a = pm[0][tid], c = pn[0][tid];
#pragma unroll
    for (int g = 1; g < 4; ++g) {
      a = fmaxf(a, pm[g][tid]);
      c = fminf(c, pn[g][tid]);
    }
    in1[tid] = x1bi[tid];
    in1[48 + tid] = a;
    in1[80 + tid] = c;
  } else if (tid < 48) {
    in1[tid] = x0[b * P0 + (tid - 32)];
  }
  __syncthreads();

  // Hidden layers: tid<128 -> arity-1 (112 in), tid>=128 -> diagonal (128 in).
  if (tid < 128) {
    float s = b1_1[tid];
    for (int k = 0; k < 112; ++k) s += in1[k] * W1_1[k * HH + tid];
    hid1[tid] = sigm(s);
  } else {
    const int h = tid - 128;
    float s = lb1[h];
    for (int k = 0; k < 128; ++k) s += in2[k] * W1[k * HH + h];
    hid2[h] = sigm(s);
  }
  __syncthreads();

  // Output layers.
  if (tid < 32) {
    float s = b2_1[tid];
    for (int k = 0; k < 128; ++k) s += hid1[k] * W2_1[k * P1 + tid];
    out1[rowI * P1 + tid] = sigm(s);
  } else if (tid >= 128 && tid < 160) {
    const int p = tid - 128;
    float s = b2[p];
    for (int k = 0; k < 128; ++k) s += hid2[k] * W2[k * P2 + p];
    out2[(rowI * NN + i) * P2 + p] = sigm(s);
  }
}

extern "C" void kernel_launch(void* const* d_in, const int* in_sizes, int n_in,
                              void* d_out, int out_size, void* d_ws, size_t ws_size,
                              hipStream_t stream) {
  const float* x0   = (const float*)d_in[0];
  const float* x1   = (const float*)d_in[1];
  const float* x2   = (const float*)d_in[2];
  const float* W1_0 = (const float*)d_in[3];
  const float* b1_0 = (const float*)d_in[4];
  const float* W2_0 = (const float*)d_in[5];
  const float* b2_0 = (const float*)d_in[6];
  const float* W1_1 = (const float*)d_in[7];
  const float* b1_1 = (const float*)d_in[8];
  const float* W2_1 = (const float*)d_in[9];
  const float* b2_1 = (const float*)d_in[10];
  const float* W1_2 = (const float*)d_in[11];
  const float* b1_2 = (const float*)d_in[12];
  const float* W2_2 = (const float*)d_in[13];
  const float* b2_2 = (const float*)d_in[14];

  float* out0 = (float*)d_out;
  float* out1 = out0 + (size_t)BB * P0;
  float* out2 = out1 + (size_t)BB * NN * P1;

  hipLaunchKernelGGL(k_fused, dim3(1026), dim3(256), 0, stream,
                     x0, x1, x2, W1_2, b1_2, W2_2, b2_2,
                     W1_1, b1_1, W2_1, b2_1,
                     W1_0, b1_0, W2_0, b2_0,
                     out0, out1, out2);
}